// Round 1
// baseline (428.525 us; speedup 1.0000x reference)
//
#include <hip/hip_runtime.h>

#define TPB 256

// ---------------- kernels ----------------

__global__ void k_deg_init(float* deg, int N) {
    int i = blockIdx.x * blockDim.x + threadIdx.x;
    if (i < N) deg[i] = 1.0f;  // self-loop
}

__global__ void k_deg_scatter(const int* dst, float* deg, int E) {
    int e = blockIdx.x * blockDim.x + threadIdx.x;
    if (e < E) atomicAdd(&deg[dst[e]], 1.0f);
}

// dinv = rsqrt(deg) (in place); u = dinv*x; s_raw init with self-loop term u[i]
__global__ void k_dinv_u(const float* x, float* deg_dinv, float* u, float* s_raw, int N) {
    int i = blockIdx.x * blockDim.x + threadIdx.x;
    if (i < N) {
        float dv = rsqrtf(deg_dinv[i]);
        deg_dinv[i] = dv;
        float ui = dv * x[i];
        u[i] = ui;
        s_raw[i] = ui;
    }
}

// s_raw[dst] += u[src]   (scalar layer-1 propagation)
__global__ void k_s_scatter(const int* src, const int* dst, const float* u, float* s_raw, int E) {
    int e = blockIdx.x * blockDim.x + threadIdx.x;
    if (e < E) atomicAdd(&s_raw[dst[e]], u[src[e]]);
}

// M = W2 @ Wf  (64x16); bb = b2 @ Wf + bf  (16)
__global__ void k_Mbb(const float* W2, const float* Wf, const float* b2, const float* bf,
                      float* M, float* bb) {
    int t = threadIdx.x;           // single block of 1024
    int f = t >> 4, o = t & 15;
    float a = 0.f;
    for (int k = 0; k < 64; ++k) a = fmaf(W2[f * 64 + k], Wf[k * 16 + o], a);
    M[t] = a;
    if (t < 16) {
        float c = 0.f;
        for (int k = 0; k < 64; ++k) c = fmaf(b2[k], Wf[k * 16 + t], c);
        bb[t] = c + bf[t];
    }
}

// per node: s = dinv*s_raw; h1[f] = relu(s*W1[f]+b1[f]); zd = dinv * (h1 @ M)
// acc initialized with zd (self-loop term of layer-2 propagation)
__global__ void k_node_z(const float* dinv, const float* s_raw,
                         const float* W1, const float* b1, const float* M,
                         float* zd, float* acc, int N) {
    __shared__ float sW1[64], sb1[64], sM[1024];
    int t = threadIdx.x;
    if (t < 64) { sW1[t] = W1[t]; sb1[t] = b1[t]; }
    for (int j = t; j < 1024; j += blockDim.x) sM[j] = M[j];
    __syncthreads();
    int i = blockIdx.x * blockDim.x + t;
    if (i >= N) return;
    float dv = dinv[i];
    float s  = dv * s_raw[i];
    float za[16];
#pragma unroll
    for (int o = 0; o < 16; ++o) za[o] = 0.f;
    for (int f = 0; f < 64; ++f) {
        float hf = fmaxf(fmaf(s, sW1[f], sb1[f]), 0.f);
#pragma unroll
        for (int o = 0; o < 16; ++o) za[o] = fmaf(hf, sM[f * 16 + o], za[o]);
    }
#pragma unroll
    for (int o = 0; o < 16; ++o) {
        float v = dv * za[o];
        zd[i * 16 + o]  = v;
        acc[i * 16 + o] = v;
    }
}

// acc[dst][o] += zd[src][o]   (16 lanes per edge)
__global__ void k_edge_scatter(const int* src, const int* dst, const float* zd,
                               float* acc, int E) {
    int t = blockIdx.x * blockDim.x + threadIdx.x;
    int e = t >> 4, o = t & 15;
    if (e >= E) return;
    int s = src[e], d = dst[e];
    atomicAdd(&acc[d * 16 + o], zd[s * 16 + o]);
}

__global__ void k_zero(float* p, int n) {
    int i = blockIdx.x * blockDim.x + threadIdx.x;
    if (i < n) p[i] = 0.f;
}

// gsum[batch[i]][o] += dinv[i]*acc[i][o]; cnt[batch[i]] += 1
__global__ void k_pool(const int* batch, const float* dinv, const float* acc,
                       float* gsum, float* cnt, int N) {
    int t = blockIdx.x * blockDim.x + threadIdx.x;
    int i = t >> 4, o = t & 15;
    if (i >= N) return;
    int g = batch[i];
    float v = dinv[i] * acc[i * 16 + o];
    atomicAdd(&gsum[g * 16 + o], v);
    if (o == 0) atomicAdd(&cnt[g], 1.0f);
}

__global__ void k_final(const float* gsum, const float* cnt, const float* bb,
                        float* out, int G) {
    int t = blockIdx.x * blockDim.x + threadIdx.x;
    int g = t >> 4, o = t & 15;
    if (g >= G) return;
    out[t] = gsum[t] / fmaxf(cnt[g], 1.0f) + bb[o];
}

// ---------------- launch ----------------

static inline int cdiv(int a, int b) { return (a + b - 1) / b; }

extern "C" void kernel_launch(void* const* d_in, const int* in_sizes, int n_in,
                              void* d_out, int out_size, void* d_ws, size_t ws_size,
                              hipStream_t stream) {
    const float* x   = (const float*)d_in[0];
    const int*   ei  = (const int*)d_in[1];   // [2,E] row-major: src then dst
    const int*   bat = (const int*)d_in[2];
    const float* W1  = (const float*)d_in[4];
    const float* b1  = (const float*)d_in[5];
    const float* W2  = (const float*)d_in[6];
    const float* b2  = (const float*)d_in[7];
    const float* Wf  = (const float*)d_in[8];
    const float* bf  = (const float*)d_in[9];
    float* out = (float*)d_out;

    const int N = in_sizes[0];        // Fin = 1
    const int E = in_sizes[1] / 2;
    const int G = out_size / 16;

    const int* src = ei;
    const int* dst = ei + E;

    // workspace layout (floats)
    float* w     = (float*)d_ws;
    float* dinv  = w;                 // [N]   deg -> dinv in place
    float* u     = dinv + N;          // [N]
    float* s_raw = u + N;             // [N]
    float* zd    = s_raw + N;         // [16N]
    float* acc   = zd + (size_t)16 * N;   // [16N]
    float* gsum  = acc + (size_t)16 * N;  // [16G]
    float* cnt   = gsum + (size_t)16 * G; // [G]
    float* M     = cnt + G;           // [1024]
    float* bb    = M + 1024;          // [16]

    // degrees
    k_deg_init<<<cdiv(N, TPB), TPB, 0, stream>>>(dinv, N);
    k_deg_scatter<<<cdiv(E, TPB), TPB, 0, stream>>>(dst, dinv, E);
    k_dinv_u<<<cdiv(N, TPB), TPB, 0, stream>>>(x, dinv, u, s_raw, N);

    // layer-1 scalar propagation
    k_s_scatter<<<cdiv(E, TPB), TPB, 0, stream>>>(src, dst, u, s_raw, E);

    // folded weights
    k_Mbb<<<1, 1024, 0, stream>>>(W2, Wf, b2, bf, M, bb);

    // per-node z (pre-scaled by dinv), acc init with self-loop
    k_node_z<<<cdiv(N, TPB), TPB, 0, stream>>>(dinv, s_raw, W1, b1, M, zd, acc, N);

    // layer-2 propagation (16-wide, folded through W2@Wf)
    {
        long long tot = (long long)E * 16;
        k_edge_scatter<<<cdiv((int)tot, TPB), TPB, 0, stream>>>(src, dst, zd, acc, E);
    }

    // pooling
    k_zero<<<cdiv(16 * G + G, TPB), TPB, 0, stream>>>(gsum, 16 * G + G);  // gsum+cnt contiguous
    k_pool<<<cdiv(N * 16, TPB), TPB, 0, stream>>>(bat, dinv, acc, gsum, cnt, N);

    // finalize
    k_final<<<cdiv(G * 16, TPB), TPB, 0, stream>>>(gsum, cnt, bb, out, G);
}

// Round 3
// 318.087 us; speedup vs baseline: 1.3472x; 1.3472x over previous
//
#include <hip/hip_runtime.h>

#define TPB 256

// ---------------- kernels ----------------

__global__ void k_deg_init(float* deg, int N) {
    int i = blockIdx.x * blockDim.x + threadIdx.x;
    if (i < N) deg[i] = 1.0f;  // self-loop
}

__global__ void k_deg_scatter(const int* dst, float* deg, int E) {
    int e = blockIdx.x * blockDim.x + threadIdx.x;
    if (e < E) atomicAdd(&deg[dst[e]], 1.0f);
}

// dinv = rsqrt(deg) (in place); u = dinv*x; s_raw init with self-loop term u[i]
__global__ void k_dinv_u(const float* x, float* deg_dinv, float* u, float* s_raw, int N) {
    int i = blockIdx.x * blockDim.x + threadIdx.x;
    if (i < N) {
        float dv = rsqrtf(deg_dinv[i]);
        deg_dinv[i] = dv;
        float ui = dv * x[i];
        u[i] = ui;
        s_raw[i] = ui;
    }
}

// s_raw[dst] += u[src]   (scalar layer-1 propagation)
__global__ void k_s_scatter(const int* src, const int* dst, const float* u, float* s_raw, int E) {
    int e = blockIdx.x * blockDim.x + threadIdx.x;
    if (e < E) atomicAdd(&s_raw[dst[e]], u[src[e]]);
}

// M = W2 @ Wf  (64x16); bb = b2 @ Wf + bf  (16)
__global__ void k_Mbb(const float* W2, const float* Wf, const float* b2, const float* bf,
                      float* M, float* bb) {
    int t = threadIdx.x;           // single block of 1024
    int f = t >> 4, o = t & 15;
    float a = 0.f;
    for (int k = 0; k < 64; ++k) a = fmaf(W2[f * 64 + k], Wf[k * 16 + o], a);
    M[t] = a;
    if (t < 16) {
        float c = 0.f;
        for (int k = 0; k < 64; ++k) c = fmaf(b2[k], Wf[k * 16 + t], c);
        bb[t] = c + bf[t];
    }
}

// per node: s = dinv*s_raw; h1[f] = relu(s*W1[f]+b1[f]); zd = dinv * (h1 @ M)
// acc initialized with zd (self-loop term of layer-2 propagation)
__global__ void k_node_z(const float* dinv, const float* s_raw,
                         const float* W1, const float* b1, const float* M,
                         float* zd, float* acc, int N) {
    __shared__ float sW1[64], sb1[64], sM[1024];
    int t = threadIdx.x;
    if (t < 64) { sW1[t] = W1[t]; sb1[t] = b1[t]; }
    for (int j = t; j < 1024; j += blockDim.x) sM[j] = M[j];
    __syncthreads();
    int i = blockIdx.x * blockDim.x + t;
    if (i >= N) return;
    float dv = dinv[i];
    float s  = dv * s_raw[i];
    float za[16];
#pragma unroll
    for (int o = 0; o < 16; ++o) za[o] = 0.f;
    for (int f = 0; f < 64; ++f) {
        float hf = fmaxf(fmaf(s, sW1[f], sb1[f]), 0.f);
#pragma unroll
        for (int o = 0; o < 16; ++o) za[o] = fmaf(hf, sM[f * 16 + o], za[o]);
    }
#pragma unroll
    for (int o = 0; o < 16; ++o) {
        float v = dv * za[o];
        zd[i * 16 + o]  = v;
        acc[i * 16 + o] = v;
    }
}

// acc[dst][o] += zd[src][o]   (16 lanes per edge)
__global__ void k_edge_scatter(const int* src, const int* dst, const float* zd,
                               float* acc, int E) {
    int t = blockIdx.x * blockDim.x + threadIdx.x;
    int e = t >> 4, o = t & 15;
    if (e >= E) return;
    int s = src[e], d = dst[e];
    atomicAdd(&acc[d * 16 + o], zd[s * 16 + o]);
}

__global__ void k_zero(float* p, int n) {
    int i = blockIdx.x * blockDim.x + threadIdx.x;
    if (i < n) p[i] = 0.f;
}

// gsum[batch[i]][o] += dinv[i]*acc[i][o]; cnt[batch[i]] += count
// Block = 16 consecutive nodes x 16 output lanes. batch is sorted, so most
// blocks are single-graph: LDS-reduce then ONE atomicAdd per (g,o) per block.
// Boundary blocks fall back to per-node atomics (same math as before).
__global__ void k_pool(const int* batch, const float* dinv, const float* acc,
                       float* gsum, float* cnt, int N) {
    const int t = threadIdx.x, o = t & 15, row = t >> 4;
    const int i0 = blockIdx.x * 16;
    const int i = i0 + row;
    const bool valid = i < N;
    float v = 0.f;
    int g = 0;
    if (valid) { g = batch[i]; v = dinv[i] * acc[i * 16 + o]; }

    __shared__ int s_g0, s_g1, s_nvalid;
    if (t == 0) {
        s_g0 = batch[i0];
        int ilast = min(i0 + 15, N - 1);
        s_g1 = batch[ilast];
        s_nvalid = min(N - i0, 16);
    }
    __shared__ float red[16][17];
    red[row][o] = v;
    __syncthreads();

    if (s_g0 == s_g1) {
        // whole block in one graph: single atomic per output lane
        if (t < 16) {
            float a = 0.f;
#pragma unroll
            for (int r = 0; r < 16; ++r) a += red[r][t];
            atomicAdd(&gsum[s_g0 * 16 + t], a);
            if (t == 0) atomicAdd(&cnt[s_g0], (float)s_nvalid);
        }
    } else {
        // graph boundary inside the block: per-node atomics
        if (valid) {
            atomicAdd(&gsum[g * 16 + o], v);
            if (o == 0) atomicAdd(&cnt[g], 1.0f);
        }
    }
}

__global__ void k_final(const float* gsum, const float* cnt, const float* bb,
                        float* out, int G) {
    int t = blockIdx.x * blockDim.x + threadIdx.x;
    int g = t >> 4, o = t & 15;
    if (g >= G) return;
    out[t] = gsum[t] / fmaxf(cnt[g], 1.0f) + bb[o];
}

// ---------------- launch ----------------

static inline int cdiv(int a, int b) { return (a + b - 1) / b; }

extern "C" void kernel_launch(void* const* d_in, const int* in_sizes, int n_in,
                              void* d_out, int out_size, void* d_ws, size_t ws_size,
                              hipStream_t stream) {
    const float* x   = (const float*)d_in[0];
    const int*   ei  = (const int*)d_in[1];   // [2,E] row-major: src then dst
    const int*   bat = (const int*)d_in[2];
    const float* W1  = (const float*)d_in[4];
    const float* b1  = (const float*)d_in[5];
    const float* W2  = (const float*)d_in[6];
    const float* b2  = (const float*)d_in[7];
    const float* Wf  = (const float*)d_in[8];
    const float* bf  = (const float*)d_in[9];
    float* out = (float*)d_out;

    const int N = in_sizes[0];        // Fin = 1
    const int E = in_sizes[1] / 2;
    const int G = out_size / 16;

    const int* src = ei;
    const int* dst = ei + E;

    // workspace layout (floats)
    float* w     = (float*)d_ws;
    float* dinv  = w;                 // [N]   deg -> dinv in place
    float* u     = dinv + N;          // [N]
    float* s_raw = u + N;             // [N]
    float* zd    = s_raw + N;         // [16N]
    float* acc   = zd + (size_t)16 * N;   // [16N]
    float* gsum  = acc + (size_t)16 * N;  // [16G]
    float* cnt   = gsum + (size_t)16 * G; // [G]
    float* M     = cnt + G;           // [1024]
    float* bb    = M + 1024;          // [16]

    // degrees
    k_deg_init<<<cdiv(N, TPB), TPB, 0, stream>>>(dinv, N);
    k_deg_scatter<<<cdiv(E, TPB), TPB, 0, stream>>>(dst, dinv, E);
    k_dinv_u<<<cdiv(N, TPB), TPB, 0, stream>>>(x, dinv, u, s_raw, N);

    // layer-1 scalar propagation
    k_s_scatter<<<cdiv(E, TPB), TPB, 0, stream>>>(src, dst, u, s_raw, E);

    // folded weights
    k_Mbb<<<1, 1024, 0, stream>>>(W2, Wf, b2, bf, M, bb);

    // per-node z (pre-scaled by dinv), acc init with self-loop
    k_node_z<<<cdiv(N, TPB), TPB, 0, stream>>>(dinv, s_raw, W1, b1, M, zd, acc, N);

    // layer-2 propagation (16-wide, folded through W2@Wf)
    {
        long long tot = (long long)E * 16;
        k_edge_scatter<<<cdiv((int)tot, TPB), TPB, 0, stream>>>(src, dst, zd, acc, E);
    }

    // pooling (block-local reduce + low-contention atomics)
    k_zero<<<cdiv(16 * G + G, TPB), TPB, 0, stream>>>(gsum, 16 * G + G);  // gsum+cnt contiguous
    k_pool<<<cdiv(N, 16), 256, 0, stream>>>(bat, dinv, acc, gsum, cnt, N);

    // finalize
    k_final<<<cdiv(G * 16, TPB), TPB, 0, stream>>>(gsum, cnt, bb, out, G);
}

// Round 4
// 316.272 us; speedup vs baseline: 1.3549x; 1.0057x over previous
//
#include <hip/hip_runtime.h>

#define TPB 256
#define NC 4   // privatized copies for scalar scatters

// ---------------- kernels ----------------

__global__ void k_zero(float* p, int n) {
    int i = blockIdx.x * blockDim.x + threadIdx.x;
    if (i < n) p[i] = 0.f;
}

// deg histogram into NC spread copies (copy = edge sub-index) to cut
// same-cache-line atomic serialization. 4 edges per thread via int4.
__global__ void k_deg_scatter4(const int4* dst4, float* degc, int E4, int N) {
    int t = blockIdx.x * blockDim.x + threadIdx.x;
    if (t >= E4) return;
    int4 d = dst4[t];
    atomicAdd(&degc[0 * N + d.x], 1.f);
    atomicAdd(&degc[1 * N + d.y], 1.f);
    atomicAdd(&degc[2 * N + d.z], 1.f);
    atomicAdd(&degc[3 * N + d.w], 1.f);
}

__global__ void k_deg_tail(const int* dst, float* degc, int e0, int E) {
    int e = e0 + blockIdx.x * blockDim.x + threadIdx.x;
    if (e < E) atomicAdd(&degc[dst[e]], 1.f);
}

// fold deg copies -> dinv, u; re-init A as s-copies: copy0 = u (self-loop), rest 0
__global__ void k_dinv_u(const float* x, float* A, float* dinv, float* u, int N) {
    int i = blockIdx.x * blockDim.x + threadIdx.x;
    if (i >= N) return;
    float dsum = 1.f + A[i] + A[N + i] + A[2 * N + i] + A[3 * N + i];
    float dv = rsqrtf(dsum);
    dinv[i] = dv;
    float ui = dv * x[i];
    u[i] = ui;
    A[i] = ui; A[N + i] = 0.f; A[2 * N + i] = 0.f; A[3 * N + i] = 0.f;
}

// s scatter into NC spread copies; 4 edges/thread, int4 index loads
__global__ void k_s_scatter4(const int4* src4, const int4* dst4, const float* u,
                             float* A, int E4, int N) {
    int t = blockIdx.x * blockDim.x + threadIdx.x;
    if (t >= E4) return;
    int4 s = src4[t];
    int4 d = dst4[t];
    atomicAdd(&A[0 * N + d.x], u[s.x]);
    atomicAdd(&A[1 * N + d.y], u[s.y]);
    atomicAdd(&A[2 * N + d.z], u[s.z]);
    atomicAdd(&A[3 * N + d.w], u[s.w]);
}

__global__ void k_s_tail(const int* src, const int* dst, const float* u,
                         float* A, int e0, int E) {
    int e = e0 + blockIdx.x * blockDim.x + threadIdx.x;
    if (e < E) atomicAdd(&A[dst[e]], u[src[e]]);
}

// M = W2 @ Wf  (64x16); bb = b2 @ Wf + bf  (16)
__global__ void k_Mbb(const float* W2, const float* Wf, const float* b2, const float* bf,
                      float* M, float* bb) {
    int t = threadIdx.x;           // single block of 1024
    int f = t >> 4, o = t & 15;
    float a = 0.f;
    for (int k = 0; k < 64; ++k) a = fmaf(W2[f * 64 + k], Wf[k * 16 + o], a);
    M[t] = a;
    if (t < 16) {
        float c = 0.f;
        for (int k = 0; k < 64; ++k) c = fmaf(b2[k], Wf[k * 16 + t], c);
        bb[t] = c + bf[t];
    }
}

// per node: s = dinv*(sum of s-copies); h1 = relu(s*W1+b1); zd = dinv*(h1@M)
// acc initialized with zd (self-loop term of layer-2 propagation)
__global__ void k_node_z(const float* dinv, const float* A,
                         const float* W1, const float* b1, const float* M,
                         float* zd, float* acc, int N) {
    __shared__ float sW1[64], sb1[64], sM[1024];
    int t = threadIdx.x;
    if (t < 64) { sW1[t] = W1[t]; sb1[t] = b1[t]; }
    for (int j = t; j < 1024; j += blockDim.x) sM[j] = M[j];
    __syncthreads();
    int i = blockIdx.x * blockDim.x + t;
    if (i >= N) return;
    float dv = dinv[i];
    float s = dv * (A[i] + A[N + i] + A[2 * N + i] + A[3 * N + i]);
    float za[16];
#pragma unroll
    for (int o = 0; o < 16; ++o) za[o] = 0.f;
    for (int f = 0; f < 64; ++f) {
        float hf = fmaxf(fmaf(s, sW1[f], sb1[f]), 0.f);
#pragma unroll
        for (int o = 0; o < 16; ++o) za[o] = fmaf(hf, sM[f * 16 + o], za[o]);
    }
#pragma unroll
    for (int o = 0; o < 16; ++o) {
        float v = dv * za[o];
        zd[i * 16 + o]  = v;
        acc[i * 16 + o] = v;
    }
}

// acc[dst][o] += zd[src][o]   (16 lanes per edge)
__global__ void k_edge_scatter(const int* src, const int* dst, const float* zd,
                               float* acc, int E) {
    int t = blockIdx.x * blockDim.x + threadIdx.x;
    int e = t >> 4, o = t & 15;
    if (e >= E) return;
    int s = src[e], d = dst[e];
    atomicAdd(&acc[d * 16 + o], zd[s * 16 + o]);
}

// block = 16 consecutive nodes x 16 lanes; sorted batch -> most blocks are
// single-graph: LDS reduce then one atomic per (g,o); boundary blocks fall back.
__global__ void k_pool(const int* batch, const float* dinv, const float* acc,
                       float* gsum, float* cnt, int N) {
    const int t = threadIdx.x, o = t & 15, row = t >> 4;
    const int i0 = blockIdx.x * 16;
    const int i = i0 + row;
    const bool valid = i < N;
    float v = 0.f;
    int g = 0;
    if (valid) { g = batch[i]; v = dinv[i] * acc[i * 16 + o]; }

    __shared__ int s_g0, s_g1, s_nvalid;
    if (t == 0) {
        s_g0 = batch[i0];
        int ilast = min(i0 + 15, N - 1);
        s_g1 = batch[ilast];
        s_nvalid = min(N - i0, 16);
    }
    __shared__ float red[16][17];
    red[row][o] = v;
    __syncthreads();

    if (s_g0 == s_g1) {
        if (t < 16) {
            float a = 0.f;
#pragma unroll
            for (int r = 0; r < 16; ++r) a += red[r][t];
            atomicAdd(&gsum[s_g0 * 16 + t], a);
            if (t == 0) atomicAdd(&cnt[s_g0], (float)s_nvalid);
        }
    } else {
        if (valid) {
            atomicAdd(&gsum[g * 16 + o], v);
            if (o == 0) atomicAdd(&cnt[g], 1.0f);
        }
    }
}

__global__ void k_final(const float* gsum, const float* cnt, const float* bb,
                        float* out, int G) {
    int t = blockIdx.x * blockDim.x + threadIdx.x;
    int g = t >> 4, o = t & 15;
    if (g >= G) return;
    out[t] = gsum[t] / fmaxf(cnt[g], 1.0f) + bb[o];
}

// ---------------- launch ----------------

static inline int cdiv(int a, int b) { return (a + b - 1) / b; }

extern "C" void kernel_launch(void* const* d_in, const int* in_sizes, int n_in,
                              void* d_out, int out_size, void* d_ws, size_t ws_size,
                              hipStream_t stream) {
    const float* x   = (const float*)d_in[0];
    const int*   ei  = (const int*)d_in[1];   // [2,E] row-major: src then dst
    const int*   bat = (const int*)d_in[2];
    const float* W1  = (const float*)d_in[4];
    const float* b1  = (const float*)d_in[5];
    const float* W2  = (const float*)d_in[6];
    const float* b2  = (const float*)d_in[7];
    const float* Wf  = (const float*)d_in[8];
    const float* bf  = (const float*)d_in[9];
    float* out = (float*)d_out;

    const int N = in_sizes[0];        // Fin = 1
    const int E = in_sizes[1] / 2;
    const int G = out_size / 16;

    const int* src = ei;
    const int* dst = ei + E;
    const int E4 = E / 4, Erem0 = E4 * 4;

    // workspace layout (floats)
    float* w    = (float*)d_ws;
    float* A    = w;                    // [4N]  deg copies -> s copies (reused)
    float* dinv = A + (size_t)NC * N;   // [N]
    float* u    = dinv + N;             // [N]
    float* zd   = u + N;                // [16N]
    float* acc  = zd + (size_t)16 * N;  // [16N]
    float* gsum = acc + (size_t)16 * N; // [16G]
    float* cnt  = gsum + (size_t)16 * G;// [G]
    float* M    = cnt + G;              // [1024]
    float* bb   = M + 1024;             // [16]

    // deg histogram (privatized copies)
    k_zero<<<cdiv(NC * N, TPB), TPB, 0, stream>>>(A, NC * N);
    k_deg_scatter4<<<cdiv(E4, TPB), TPB, 0, stream>>>((const int4*)dst, A, E4, N);
    if (Erem0 < E)
        k_deg_tail<<<1, TPB, 0, stream>>>(dst, A, Erem0, E);

    // fold deg -> dinv, u; re-init A as s-copies
    k_dinv_u<<<cdiv(N, TPB), TPB, 0, stream>>>(x, A, dinv, u, N);

    // layer-1 scalar propagation (privatized copies)
    k_s_scatter4<<<cdiv(E4, TPB), TPB, 0, stream>>>((const int4*)src, (const int4*)dst, u, A, E4, N);
    if (Erem0 < E)
        k_s_tail<<<1, TPB, 0, stream>>>(src, dst, u, A, Erem0, E);

    // folded weights
    k_Mbb<<<1, 1024, 0, stream>>>(W2, Wf, b2, bf, M, bb);

    // per-node z (pre-scaled by dinv), acc init with self-loop
    k_node_z<<<cdiv(N, TPB), TPB, 0, stream>>>(dinv, A, W1, b1, M, zd, acc, N);

    // layer-2 propagation (16-wide, folded through W2@Wf)
    {
        long long tot = (long long)E * 16;
        k_edge_scatter<<<cdiv((int)tot, TPB), TPB, 0, stream>>>(src, dst, zd, acc, E);
    }

    // pooling + finalize
    k_zero<<<cdiv(16 * G + G, TPB), TPB, 0, stream>>>(gsum, 16 * G + G);
    k_pool<<<cdiv(N, 16), 256, 0, stream>>>(bat, dinv, acc, gsum, cnt, N);
    k_final<<<cdiv(G * 16, TPB), TPB, 0, stream>>>(gsum, cnt, bb, out, G);
}

// Round 5
// 218.443 us; speedup vs baseline: 1.9617x; 1.4478x over previous
//
#include <hip/hip_runtime.h>

#define TPB 256
#define SCAN_BLK 1024

// ---------------- kernels ----------------

__global__ void k_zero_i(int* p, int n) {
    int i = blockIdx.x * blockDim.x + threadIdx.x;
    if (i < n) p[i] = 0;
}

__global__ void k_zero_f(float* p, int n) {
    int i = blockIdx.x * blockDim.x + threadIdx.x;
    if (i < n) p[i] = 0.f;
}

// the ONLY big atomic pass: histogram of dst + per-edge rank capture
__global__ void k_rank(const int* dst, int* cnt, int* rank, int E) {
    int e = blockIdx.x * blockDim.x + threadIdx.x;
    if (e < E) rank[e] = atomicAdd(&cnt[dst[e]], 1);
}

// block-level inclusive scan (1024 items/block) + block sums
__global__ void k_scan1(const int* cnt, int* incl, int* bsum, int N) {
    __shared__ int sh[SCAN_BLK];
    int t = threadIdx.x;
    int i = blockIdx.x * SCAN_BLK + t;
    int v = (i < N) ? cnt[i] : 0;
    sh[t] = v;
    __syncthreads();
    for (int off = 1; off < SCAN_BLK; off <<= 1) {
        int a = (t >= off) ? sh[t - off] : 0;
        __syncthreads();
        sh[t] += a;
        __syncthreads();
    }
    if (i < N) incl[i] = sh[t];
    if (t == SCAN_BLK - 1) bsum[blockIdx.x] = sh[t];
}

// exclusive scan of block sums (single block, NB <= 128)
__global__ void k_scan2(int* bsum, int NB) {
    __shared__ int sh[128];
    int t = threadIdx.x;
    int v = (t < NB) ? bsum[t] : 0;
    sh[t] = v;
    __syncthreads();
    for (int off = 1; off < 128; off <<= 1) {
        int a = (t >= off) ? sh[t - off] : 0;
        __syncthreads();
        sh[t] += a;
        __syncthreads();
    }
    if (t < NB) bsum[t] = sh[t] - v;  // exclusive
}

// finalize: rowStart (exclusive scan, written over incl), dinv, u
__global__ void k_scan3(const float* x, const int* cnt, int* incl_rowstart,
                        const int* bsum, float* dinv, float* u, int N) {
    int t = threadIdx.x;
    int i = blockIdx.x * SCAN_BLK + t;
    if (i >= N) return;
    int c = cnt[i];
    incl_rowstart[i] = incl_rowstart[i] - c + bsum[blockIdx.x];
    float dv = rsqrtf(1.f + (float)c);
    dinv[i] = dv;
    u[i] = dv * x[i];
}

// CSR fill with plain (L2-absorbed) stores — no atomics
__global__ void k_csr_fill(const int* dst, const int* rank, const int* rowStart,
                           int* csr, int E) {
    int e = blockIdx.x * blockDim.x + threadIdx.x;
    if (e < E) csr[rowStart[dst[e]] + rank[e]] = e;  // store edge id? no — store src
}

// (separate to keep csr_fill trivially simple: store src directly)
__global__ void k_csr_fill_src(const int* src, const int* dst, const int* rank,
                               const int* rowStart, int* csr, int E) {
    int e = blockIdx.x * blockDim.x + threadIdx.x;
    if (e < E) csr[rowStart[dst[e]] + rank[e]] = src[e];
}

// M = W2 @ Wf  (64x16); bb = b2 @ Wf + bf  (16)
__global__ void k_Mbb(const float* W2, const float* Wf, const float* b2, const float* bf,
                      float* M, float* bb) {
    int t = threadIdx.x;           // single block of 1024
    int f = t >> 4, o = t & 15;
    float a = 0.f;
    for (int k = 0; k < 64; ++k) a = fmaf(W2[f * 64 + k], Wf[k * 16 + o], a);
    M[t] = a;
    if (t < 16) {
        float c = 0.f;
        for (int k = 0; k < 64; ++k) c = fmaf(b2[k], Wf[k * 16 + t], c);
        bb[t] = c + bf[t];
    }
}

// per node: s-gather over CSR + layer-1 + fold: zd = dinv * (relu(s*W1+b1) @ M)
__global__ void k_node(const int* rowStart, const int* cnt, const int* csr,
                       const float* u, const float* dinv,
                       const float* W1, const float* b1, const float* M,
                       float* zd, int N) {
    __shared__ float sW1[64], sb1[64], sM[1024];
    int t = threadIdx.x;
    if (t < 64) { sW1[t] = W1[t]; sb1[t] = b1[t]; }
    for (int j = t; j < 1024; j += blockDim.x) sM[j] = M[j];
    __syncthreads();
    int i = blockIdx.x * blockDim.x + t;
    if (i >= N) return;
    float dv = dinv[i];
    float ssum = u[i];                       // self-loop
    int rs = rowStart[i], dg = cnt[i];
    for (int k = 0; k < dg; ++k) ssum += u[csr[rs + k]];
    float s = dv * ssum;
    float za[16];
#pragma unroll
    for (int o = 0; o < 16; ++o) za[o] = 0.f;
    for (int f = 0; f < 64; ++f) {
        float hf = fmaxf(fmaf(s, sW1[f], sb1[f]), 0.f);
#pragma unroll
        for (int o = 0; o < 16; ++o) za[o] = fmaf(hf, sM[f * 16 + o], za[o]);
    }
#pragma unroll
    for (int o = 0; o < 16; ++o) zd[i * 16 + o] = dv * za[o];
}

// layer-2 gather + mean-pool, fused. Block = 16 nodes x 16 lanes.
__global__ void k_gather_pool(const int* batch, const int* rowStart, const int* cnt,
                              const int* csr, const float* zd, const float* dinv,
                              float* gsum, float* cntf, int N) {
    const int t = threadIdx.x, o = t & 15, row = t >> 4;
    const int i0 = blockIdx.x * 16;
    const int i = i0 + row;
    const bool valid = i < N;
    float v = 0.f;
    int g = 0;
    if (valid) {
        g = batch[i];
        float a = zd[i * 16 + o];            // self-loop term
        int rs = rowStart[i], dg = cnt[i];
        for (int k = 0; k < dg; ++k) {
            int s = csr[rs + k];             // broadcast within the 16-lane group
            a += zd[s * 16 + o];             // 64B coalesced per group
        }
        v = dinv[i] * a;
    }

    __shared__ int s_g0, s_g1, s_nvalid;
    if (t == 0) {
        s_g0 = batch[i0];
        int ilast = min(i0 + 15, N - 1);
        s_g1 = batch[ilast];
        s_nvalid = min(N - i0, 16);
    }
    __shared__ float red[16][17];
    red[row][o] = v;
    __syncthreads();

    if (s_g0 == s_g1) {
        if (t < 16) {
            float a = 0.f;
#pragma unroll
            for (int r = 0; r < 16; ++r) a += red[r][t];
            atomicAdd(&gsum[s_g0 * 16 + t], a);
            if (t == 0) atomicAdd(&cntf[s_g0], (float)s_nvalid);
        }
    } else {
        if (valid) {
            atomicAdd(&gsum[g * 16 + o], v);
            if (o == 0) atomicAdd(&cntf[g], 1.0f);
        }
    }
}

__global__ void k_final(const float* gsum, const float* cntf, const float* bb,
                        float* out, int G) {
    int t = blockIdx.x * blockDim.x + threadIdx.x;
    int g = t >> 4, o = t & 15;
    if (g >= G) return;
    out[t] = gsum[t] / fmaxf(cntf[g], 1.0f) + bb[o];
}

// ---------------- launch ----------------

static inline int cdiv(int a, int b) { return (a + b - 1) / b; }

extern "C" void kernel_launch(void* const* d_in, const int* in_sizes, int n_in,
                              void* d_out, int out_size, void* d_ws, size_t ws_size,
                              hipStream_t stream) {
    const float* x   = (const float*)d_in[0];
    const int*   ei  = (const int*)d_in[1];   // [2,E]: src then dst
    const int*   bat = (const int*)d_in[2];
    const float* W1  = (const float*)d_in[4];
    const float* b1  = (const float*)d_in[5];
    const float* W2  = (const float*)d_in[6];
    const float* b2  = (const float*)d_in[7];
    const float* Wf  = (const float*)d_in[8];
    const float* bf  = (const float*)d_in[9];
    float* out = (float*)d_out;

    const int N = in_sizes[0];        // Fin = 1
    const int E = in_sizes[1] / 2;
    const int G = out_size / 16;
    const int NB = cdiv(N, SCAN_BLK);  // <= 128

    const int* src = ei;
    const int* dst = ei + E;

    // workspace layout (4B elems). zd overlays rank (rank dead after csr_fill).
    char* w = (char*)d_ws;
    int*   cnt      = (int*)w;                     w += (size_t)N * 4;     // [N]
    int*   rowStart = (int*)w;                     w += (size_t)N * 4;     // [N] (incl scan in place)
    float* dinv     = (float*)w;                   w += (size_t)N * 4;     // [N]
    float* u        = (float*)w;                   w += (size_t)N * 4;     // [N]
    int*   bsum     = (int*)w;                     w += 128 * 4;           // [128]
    int*   csr      = (int*)w;                     w += (size_t)E * 4;     // [E]
    int*   rank     = (int*)w;                                             // [E] ...
    float* zd       = (float*)rank;                w += (size_t)(E > 16 * N ? E : 16 * N) * 4;  // overlay [16N]
    float* gsum     = (float*)w;                   w += (size_t)16 * G * 4;
    float* cntf     = (float*)w;                   w += (size_t)G * 4;
    float* M        = (float*)w;                   w += 1024 * 4;
    float* bb       = (float*)w;

    // 1) histogram + rank (the single big atomic pass)
    k_zero_i<<<cdiv(N, TPB), TPB, 0, stream>>>(cnt, N);
    k_rank<<<cdiv(E, TPB), TPB, 0, stream>>>(dst, cnt, rank, E);

    // 2) prefix scan -> rowStart; fused dinv/u
    k_scan1<<<NB, SCAN_BLK, 0, stream>>>(cnt, rowStart, bsum, N);
    k_scan2<<<1, 128, 0, stream>>>(bsum, NB);
    k_scan3<<<NB, SCAN_BLK, 0, stream>>>(x, cnt, rowStart, bsum, dinv, u, N);

    // 3) CSR fill (plain stores, L2-absorbed)
    k_csr_fill_src<<<cdiv(E, TPB), TPB, 0, stream>>>(src, dst, rank, rowStart, csr, E);

    // 4) folded weights
    k_Mbb<<<1, 1024, 0, stream>>>(W2, Wf, b2, bf, M, bb);

    // 5) layer-1 gather + transform -> zd (overlays rank, now dead)
    k_node<<<cdiv(N, TPB), TPB, 0, stream>>>(rowStart, cnt, csr, u, dinv, W1, b1, M, zd, N);

    // 6) layer-2 gather + pool (no per-node acc buffer at all)
    k_zero_f<<<cdiv(16 * G + G, TPB), TPB, 0, stream>>>(gsum, 16 * G + G);
    k_gather_pool<<<cdiv(N, 16), 256, 0, stream>>>(bat, rowStart, cnt, csr, zd, dinv, gsum, cntf, N);

    // 7) finalize
    k_final<<<cdiv(G * 16, TPB), TPB, 0, stream>>>(gsum, cntf, bb, out, G);
}

// Round 6
// 166.942 us; speedup vs baseline: 2.5669x; 1.3085x over previous
//
#include <hip/hip_runtime.h>

#define TPB 256
#define NBUCK 512          // buckets of 256 nodes: bucket = dst >> 8
#define A2_BLOCKS 400

// ---------------- kernels ----------------

__global__ void k_zero_i(int* p, int n) {
    int i = blockIdx.x * blockDim.x + threadIdx.x;
    if (i < n) p[i] = 0;
}

__global__ void k_zero_f(float* p, int n) {
    int i = blockIdx.x * blockDim.x + threadIdx.x;
    if (i < n) p[i] = 0.f;
}

// A0: bucket histogram, LDS-privatized; ~131K global atomics total
__global__ void k_bhistA(const int* dst, int* bucketTot, int E) {
    __shared__ int sh[NBUCK];
    int t = threadIdx.x;
    sh[t] = 0; sh[t + 256] = 0;
    __syncthreads();
    for (int e = blockIdx.x * blockDim.x + t; e < E; e += gridDim.x * blockDim.x)
        atomicAdd(&sh[dst[e] >> 8], 1);
    __syncthreads();
    int c0 = sh[t], c1 = sh[t + 256];
    if (c0) atomicAdd(&bucketTot[t], c0);
    if (c1) atomicAdd(&bucketTot[t + 256], c1);
}

// A1: exclusive scan of 512 bucket totals -> base; init cursor
__global__ void k_bscan(const int* tot, int* base, int* cursor) {
    __shared__ int sh[NBUCK];
    int t = threadIdx.x;
    int v = tot[t];
    sh[t] = v;
    __syncthreads();
    for (int off = 1; off < NBUCK; off <<= 1) {
        int a = (t >= off) ? sh[t - off] : 0;
        __syncthreads();
        sh[t] += a;
        __syncthreads();
    }
    int excl = sh[t] - v;
    base[t] = excl;
    cursor[t] = excl;
    if (t == NBUCK - 1) base[NBUCK] = sh[t];
}

// A2: partition edges into bucket-contiguous regions as packed words
// word = (dst & 255) << 24 | src   (src < 2^17, local < 2^8)
__global__ void k_bscatter(const int* src, const int* dst, int* bucketCursor,
                           int* packed, int E, int chunk) {
    __shared__ int shc[NBUCK];
    __shared__ int cur[NBUCK];
    int t = threadIdx.x;
    shc[t] = 0; shc[t + 256] = 0;
    __syncthreads();
    int e0 = blockIdx.x * chunk;
    int e1 = min(E, e0 + chunk);
    for (int e = e0 + t; e < e1; e += 256)
        atomicAdd(&shc[dst[e] >> 8], 1);
    __syncthreads();
    int c0 = shc[t], c1 = shc[t + 256];
    if (c0) cur[t] = atomicAdd(&bucketCursor[t], c0);
    if (c1) cur[t + 256] = atomicAdd(&bucketCursor[t + 256], c1);
    __syncthreads();
    for (int e = e0 + t; e < e1; e += 256) {
        int d = dst[e];
        int b = d >> 8;
        int off = atomicAdd(&cur[b], 1);
        packed[off] = ((d & 255) << 24) | src[e];
    }
}

// B: per-bucket counting sort -> cnt, rowStart, dinv, u, csr (one wg per bucket)
__global__ void k_bucket_csr(const int* bucketBase, const int* packed, const float* x,
                             int* cnt, int* rowStart, float* dinv, float* u,
                             int* csr, int N) {
    __shared__ int c256[256];
    __shared__ int row256[256];
    __shared__ int cur256[256];
    const int b = blockIdx.x;
    const int t = threadIdx.x;
    const int nodeBase = b * 256;
    const int nodeCnt = min(N - nodeBase, 256);
    const int eb = bucketBase[b], ee = bucketBase[b + 1];

    c256[t] = 0;
    __syncthreads();
    for (int e = eb + t; e < ee; e += 256)
        atomicAdd(&c256[((unsigned)packed[e]) >> 24], 1);
    __syncthreads();

    // inclusive scan of c256 -> row256 (then exclusive via -c)
    int v = c256[t];
    row256[t] = v;
    __syncthreads();
    for (int off = 1; off < 256; off <<= 1) {
        int a = (t >= off) ? row256[t - off] : 0;
        __syncthreads();
        row256[t] += a;
        __syncthreads();
    }
    int excl = row256[t] - v;
    cur256[t] = excl;
    __syncthreads();

    if (t < nodeCnt) {
        int i = nodeBase + t;
        cnt[i] = v;
        rowStart[i] = eb + excl;
        float dv = rsqrtf(1.f + (float)v);
        dinv[i] = dv;
        u[i] = dv * x[i];
    }

    for (int e = eb + t; e < ee; e += 256) {
        int w = packed[e];
        int local = ((unsigned)w) >> 24;
        int s = w & 0x00FFFFFF;
        int off = atomicAdd(&cur256[local], 1);
        csr[eb + off] = s;
    }
}

// M = W2 @ Wf  (64x16); bb = b2 @ Wf + bf  (16)
__global__ void k_Mbb(const float* W2, const float* Wf, const float* b2, const float* bf,
                      float* M, float* bb) {
    int t = threadIdx.x;           // single block of 1024
    int f = t >> 4, o = t & 15;
    float a = 0.f;
    for (int k = 0; k < 64; ++k) a = fmaf(W2[f * 64 + k], Wf[k * 16 + o], a);
    M[t] = a;
    if (t < 16) {
        float c = 0.f;
        for (int k = 0; k < 64; ++k) c = fmaf(b2[k], Wf[k * 16 + t], c);
        bb[t] = c + bf[t];
    }
}

// per node: s-gather over CSR + layer-1 + fold: zd = dinv * (relu(s*W1+b1) @ M)
__global__ void k_node(const int* rowStart, const int* cnt, const int* csr,
                       const float* u, const float* dinv,
                       const float* W1, const float* b1, const float* M,
                       float* zd, int N) {
    __shared__ float sW1[64], sb1[64], sM[1024];
    int t = threadIdx.x;
    if (t < 64) { sW1[t] = W1[t]; sb1[t] = b1[t]; }
    for (int j = t; j < 1024; j += blockDim.x) sM[j] = M[j];
    __syncthreads();
    int i = blockIdx.x * blockDim.x + t;
    if (i >= N) return;
    float dv = dinv[i];
    float ssum = u[i];                       // self-loop
    int rs = rowStart[i], dg = cnt[i];
    for (int k = 0; k < dg; ++k) ssum += u[csr[rs + k]];
    float s = dv * ssum;
    float za[16];
#pragma unroll
    for (int o = 0; o < 16; ++o) za[o] = 0.f;
    for (int f = 0; f < 64; ++f) {
        float hf = fmaxf(fmaf(s, sW1[f], sb1[f]), 0.f);
#pragma unroll
        for (int o = 0; o < 16; ++o) za[o] = fmaf(hf, sM[f * 16 + o], za[o]);
    }
#pragma unroll
    for (int o = 0; o < 16; ++o) zd[i * 16 + o] = dv * za[o];
}

// layer-2 gather + mean-pool, fused. Block = 16 nodes x 16 lanes.
__global__ void k_gather_pool(const int* batch, const int* rowStart, const int* cnt,
                              const int* csr, const float* zd, const float* dinv,
                              float* gsum, float* cntf, int N) {
    const int t = threadIdx.x, o = t & 15, row = t >> 4;
    const int i0 = blockIdx.x * 16;
    const int i = i0 + row;
    const bool valid = i < N;
    float v = 0.f;
    int g = 0;
    if (valid) {
        g = batch[i];
        float a = zd[i * 16 + o];            // self-loop term
        int rs = rowStart[i], dg = cnt[i];
        for (int k = 0; k < dg; ++k) {
            int s = csr[rs + k];             // broadcast within the 16-lane group
            a += zd[s * 16 + o];             // 64B coalesced per group
        }
        v = dinv[i] * a;
    }

    __shared__ int s_g0, s_g1, s_nvalid;
    if (t == 0) {
        s_g0 = batch[i0];
        int ilast = min(i0 + 15, N - 1);
        s_g1 = batch[ilast];
        s_nvalid = min(N - i0, 16);
    }
    __shared__ float red[16][17];
    red[row][o] = v;
    __syncthreads();

    if (s_g0 == s_g1) {
        if (t < 16) {
            float a = 0.f;
#pragma unroll
            for (int r = 0; r < 16; ++r) a += red[r][t];
            atomicAdd(&gsum[s_g0 * 16 + t], a);
            if (t == 0) atomicAdd(&cntf[s_g0], (float)s_nvalid);
        }
    } else {
        if (valid) {
            atomicAdd(&gsum[g * 16 + o], v);
            if (o == 0) atomicAdd(&cntf[g], 1.0f);
        }
    }
}

__global__ void k_final(const float* gsum, const float* cntf, const float* bb,
                        float* out, int G) {
    int t = blockIdx.x * blockDim.x + threadIdx.x;
    int g = t >> 4, o = t & 15;
    if (g >= G) return;
    out[t] = gsum[t] / fmaxf(cntf[g], 1.0f) + bb[o];
}

// ---------------- launch ----------------

static inline int cdiv(int a, int b) { return (a + b - 1) / b; }

extern "C" void kernel_launch(void* const* d_in, const int* in_sizes, int n_in,
                              void* d_out, int out_size, void* d_ws, size_t ws_size,
                              hipStream_t stream) {
    const float* x   = (const float*)d_in[0];
    const int*   ei  = (const int*)d_in[1];   // [2,E]: src then dst
    const int*   bat = (const int*)d_in[2];
    const float* W1  = (const float*)d_in[4];
    const float* b1  = (const float*)d_in[5];
    const float* W2  = (const float*)d_in[6];
    const float* b2  = (const float*)d_in[7];
    const float* Wf  = (const float*)d_in[8];
    const float* bf  = (const float*)d_in[9];
    float* out = (float*)d_out;

    const int N = in_sizes[0];        // Fin = 1
    const int E = in_sizes[1] / 2;
    const int G = out_size / 16;

    const int* src = ei;
    const int* dst = ei + E;

    // workspace layout. zd overlays packed (dead after k_bucket_csr).
    char* w = (char*)d_ws;
    int*   bucketTot    = (int*)w;      w += NBUCK * 4;
    int*   bucketBase   = (int*)w;      w += (NBUCK + 1) * 4;
    int*   bucketCursor = (int*)w;      w += NBUCK * 4 + 256;  // pad
    int*   packed       = (int*)w;                 // [E] ints
    float* zd           = (float*)packed;          // [16N] overlay (16N*4 == E*4 here)
    w += (size_t)(E > 16 * N ? E : 16 * N) * 4;
    int*   csr      = (int*)w;          w += (size_t)E * 4;
    int*   cnt      = (int*)w;          w += (size_t)N * 4;
    int*   rowStart = (int*)w;          w += (size_t)N * 4;
    float* dinv     = (float*)w;        w += (size_t)N * 4;
    float* u        = (float*)w;        w += (size_t)N * 4;
    float* gsum     = (float*)w;        w += (size_t)16 * G * 4;
    float* cntf     = (float*)w;        w += (size_t)G * 4;
    float* M        = (float*)w;        w += 1024 * 4;
    float* bb       = (float*)w;

    const int chunk = cdiv(E, A2_BLOCKS);

    // CSR build: bucketed counting sort (atomics mostly in LDS)
    k_zero_i<<<1, NBUCK, 0, stream>>>(bucketTot, NBUCK);
    k_bhistA<<<256, 256, 0, stream>>>(dst, bucketTot, E);
    k_bscan<<<1, NBUCK, 0, stream>>>(bucketTot, bucketBase, bucketCursor);
    k_bscatter<<<A2_BLOCKS, 256, 0, stream>>>(src, dst, bucketCursor, packed, E, chunk);
    k_bucket_csr<<<cdiv(N, 256), 256, 0, stream>>>(bucketBase, packed, x,
                                                   cnt, rowStart, dinv, u, csr, N);

    // folded weights
    k_Mbb<<<1, 1024, 0, stream>>>(W2, Wf, b2, bf, M, bb);

    // layer-1 gather + transform -> zd (overlays packed, now dead)
    k_node<<<cdiv(N, TPB), TPB, 0, stream>>>(rowStart, cnt, csr, u, dinv, W1, b1, M, zd, N);

    // layer-2 gather + pool
    k_zero_f<<<cdiv(16 * G + G, TPB), TPB, 0, stream>>>(gsum, 16 * G + G);
    k_gather_pool<<<cdiv(N, 16), 256, 0, stream>>>(bat, rowStart, cnt, csr, zd, dinv, gsum, cntf, N);

    // finalize
    k_final<<<cdiv(G * 16, TPB), TPB, 0, stream>>>(gsum, cntf, bb, out, G);
}

// Round 7
// 143.981 us; speedup vs baseline: 2.9763x; 1.1595x over previous
//
#include <hip/hip_runtime.h>

#define TPB 256
#define NBUCK 512          // buckets of 256 nodes: bucket = dst >> 8
#define A2_BLOCKS 400

// ---------------- kernels ----------------

__global__ void k_zero_i(int* p, int n) {
    int i = blockIdx.x * blockDim.x + threadIdx.x;
    if (i < n) p[i] = 0;
}

__global__ void k_zero_f(float* p, int n) {
    int i = blockIdx.x * blockDim.x + threadIdx.x;
    if (i < n) p[i] = 0.f;
}

// A0: bucket histogram, LDS-privatized; ~131K global atomics total
__global__ void k_bhistA(const int* dst, int* bucketTot, int E) {
    __shared__ int sh[NBUCK];
    int t = threadIdx.x;
    sh[t] = 0; sh[t + 256] = 0;
    __syncthreads();
    for (int e = blockIdx.x * blockDim.x + t; e < E; e += gridDim.x * blockDim.x)
        atomicAdd(&sh[dst[e] >> 8], 1);
    __syncthreads();
    int c0 = sh[t], c1 = sh[t + 256];
    if (c0) atomicAdd(&bucketTot[t], c0);
    if (c1) atomicAdd(&bucketTot[t + 256], c1);
}

// A1: exclusive scan of 512 bucket totals -> base; init cursor
__global__ void k_bscan(const int* tot, int* base, int* cursor) {
    __shared__ int sh[NBUCK];
    int t = threadIdx.x;
    int v = tot[t];
    sh[t] = v;
    __syncthreads();
    for (int off = 1; off < NBUCK; off <<= 1) {
        int a = (t >= off) ? sh[t - off] : 0;
        __syncthreads();
        sh[t] += a;
        __syncthreads();
    }
    int excl = sh[t] - v;
    base[t] = excl;
    cursor[t] = excl;
    if (t == NBUCK - 1) base[NBUCK] = sh[t];
}

// A2: partition edges into bucket-contiguous regions as packed words
// word = (dst & 255) << 24 | src   (src < 2^17, local < 2^8)
__global__ void k_bscatter(const int* src, const int* dst, int* bucketCursor,
                           int* packed, int E, int chunk) {
    __shared__ int shc[NBUCK];
    __shared__ int cur[NBUCK];
    int t = threadIdx.x;
    shc[t] = 0; shc[t + 256] = 0;
    __syncthreads();
    int e0 = blockIdx.x * chunk;
    int e1 = min(E, e0 + chunk);
    for (int e = e0 + t; e < e1; e += 256)
        atomicAdd(&shc[dst[e] >> 8], 1);
    __syncthreads();
    int c0 = shc[t], c1 = shc[t + 256];
    if (c0) cur[t] = atomicAdd(&bucketCursor[t], c0);
    if (c1) cur[t + 256] = atomicAdd(&bucketCursor[t + 256], c1);
    __syncthreads();
    for (int e = e0 + t; e < e1; e += 256) {
        int d = dst[e];
        int b = d >> 8;
        int off = atomicAdd(&cur[b], 1);
        packed[off] = ((d & 255) << 24) | src[e];
    }
}

// B: per-bucket counting sort -> cnt, rowStart, dinv, u, csr (one wg per bucket)
__global__ void k_bucket_csr(const int* bucketBase, const int* packed, const float* x,
                             int* cnt, int* rowStart, float* dinv, float* u,
                             int* csr, int N) {
    __shared__ int c256[256];
    __shared__ int row256[256];
    __shared__ int cur256[256];
    const int b = blockIdx.x;
    const int t = threadIdx.x;
    const int nodeBase = b * 256;
    const int nodeCnt = min(N - nodeBase, 256);
    const int eb = bucketBase[b], ee = bucketBase[b + 1];

    c256[t] = 0;
    __syncthreads();
    for (int e = eb + t; e < ee; e += 256)
        atomicAdd(&c256[((unsigned)packed[e]) >> 24], 1);
    __syncthreads();

    // inclusive scan of c256 -> row256 (then exclusive via -c)
    int v = c256[t];
    row256[t] = v;
    __syncthreads();
    for (int off = 1; off < 256; off <<= 1) {
        int a = (t >= off) ? row256[t - off] : 0;
        __syncthreads();
        row256[t] += a;
        __syncthreads();
    }
    int excl = row256[t] - v;
    cur256[t] = excl;
    __syncthreads();

    if (t < nodeCnt) {
        int i = nodeBase + t;
        cnt[i] = v;
        rowStart[i] = eb + excl;
        float dv = rsqrtf(1.f + (float)v);
        dinv[i] = dv;
        u[i] = dv * x[i];
    }

    for (int e = eb + t; e < ee; e += 256) {
        int w = packed[e];
        int local = ((unsigned)w) >> 24;
        int s = w & 0x00FFFFFF;
        int off = atomicAdd(&cur256[local], 1);
        csr[eb + off] = s;
    }
}

// M = W2 @ Wf  (64x16); bb = b2 @ Wf + bf  (16)
__global__ void k_Mbb(const float* W2, const float* Wf, const float* b2, const float* bf,
                      float* M, float* bb) {
    int t = threadIdx.x;           // single block of 1024
    int f = t >> 4, o = t & 15;
    float a = 0.f;
    for (int k = 0; k < 64; ++k) a = fmaf(W2[f * 64 + k], Wf[k * 16 + o], a);
    M[t] = a;
    if (t < 16) {
        float c = 0.f;
        for (int k = 0; k < 64; ++k) c = fmaf(b2[k], Wf[k * 16 + t], c);
        bb[t] = c + bf[t];
    }
}

// per node: s-gather over CSR + layer-1 + fold: zd = dinv * (relu(s*W1+b1) @ M)
// 4-way unrolled gather with independent accumulators for MLP.
__global__ void k_node(const int* rowStart, const int* cnt, const int* csr,
                       const float* u, const float* dinv,
                       const float* W1, const float* b1, const float* M,
                       float* zd, int N) {
    __shared__ float sW1[64], sb1[64], sM[1024];
    int t = threadIdx.x;
    if (t < 64) { sW1[t] = W1[t]; sb1[t] = b1[t]; }
    for (int j = t; j < 1024; j += blockDim.x) sM[j] = M[j];
    __syncthreads();
    int i = blockIdx.x * blockDim.x + t;
    if (i >= N) return;
    float dv = dinv[i];
    int rs = rowStart[i], dg = cnt[i];
    float a0 = u[i], a1 = 0.f, a2 = 0.f, a3 = 0.f;   // a0 seeds self-loop
    int k = 0;
    for (; k + 4 <= dg; k += 4) {
        int s0 = csr[rs + k], s1 = csr[rs + k + 1], s2 = csr[rs + k + 2], s3 = csr[rs + k + 3];
        float v0 = u[s0], v1 = u[s1], v2 = u[s2], v3 = u[s3];
        a0 += v0; a1 += v1; a2 += v2; a3 += v3;
    }
    for (; k < dg; ++k) a0 += u[csr[rs + k]];
    float s = dv * ((a0 + a1) + (a2 + a3));
    float za[16];
#pragma unroll
    for (int o = 0; o < 16; ++o) za[o] = 0.f;
    for (int f = 0; f < 64; ++f) {
        float hf = fmaxf(fmaf(s, sW1[f], sb1[f]), 0.f);
#pragma unroll
        for (int o = 0; o < 16; ++o) za[o] = fmaf(hf, sM[f * 16 + o], za[o]);
    }
#pragma unroll
    for (int o = 0; o < 16; ++o) zd[i * 16 + o] = dv * za[o];
}

// layer-2 gather + mean-pool, fused. Block = 16 nodes x 16 lanes.
// 4-way unrolled zd-row gather with independent accumulators for MLP.
__global__ void k_gather_pool(const int* batch, const int* rowStart, const int* cnt,
                              const int* csr, const float* zd, const float* dinv,
                              float* gsum, float* cntf, int N) {
    const int t = threadIdx.x, o = t & 15, row = t >> 4;
    const int i0 = blockIdx.x * 16;
    const int i = i0 + row;
    const bool valid = i < N;
    float v = 0.f;
    int g = 0;
    if (valid) {
        g = batch[i];
        int rs = rowStart[i], dg = cnt[i];
        float a0 = zd[i * 16 + o], a1 = 0.f, a2 = 0.f, a3 = 0.f;  // a0 seeds self-loop
        int k = 0;
        for (; k + 4 <= dg; k += 4) {
            int s0 = csr[rs + k], s1 = csr[rs + k + 1], s2 = csr[rs + k + 2], s3 = csr[rs + k + 3];
            float v0 = zd[s0 * 16 + o];
            float v1 = zd[s1 * 16 + o];
            float v2 = zd[s2 * 16 + o];
            float v3 = zd[s3 * 16 + o];
            a0 += v0; a1 += v1; a2 += v2; a3 += v3;
        }
        for (; k < dg; ++k) a0 += zd[csr[rs + k] * 16 + o];
        v = dinv[i] * ((a0 + a1) + (a2 + a3));
    }

    __shared__ int s_g0, s_g1, s_nvalid;
    if (t == 0) {
        s_g0 = batch[i0];
        int ilast = min(i0 + 15, N - 1);
        s_g1 = batch[ilast];
        s_nvalid = min(N - i0, 16);
    }
    __shared__ float red[16][17];
    red[row][o] = v;
    __syncthreads();

    if (s_g0 == s_g1) {
        if (t < 16) {
            float a = 0.f;
#pragma unroll
            for (int r = 0; r < 16; ++r) a += red[r][t];
            atomicAdd(&gsum[s_g0 * 16 + t], a);
            if (t == 0) atomicAdd(&cntf[s_g0], (float)s_nvalid);
        }
    } else {
        if (valid) {
            atomicAdd(&gsum[g * 16 + o], v);
            if (o == 0) atomicAdd(&cntf[g], 1.0f);
        }
    }
}

__global__ void k_final(const float* gsum, const float* cntf, const float* bb,
                        float* out, int G) {
    int t = blockIdx.x * blockDim.x + threadIdx.x;
    int g = t >> 4, o = t & 15;
    if (g >= G) return;
    out[t] = gsum[t] / fmaxf(cntf[g], 1.0f) + bb[o];
}

// ---------------- launch ----------------

static inline int cdiv(int a, int b) { return (a + b - 1) / b; }

extern "C" void kernel_launch(void* const* d_in, const int* in_sizes, int n_in,
                              void* d_out, int out_size, void* d_ws, size_t ws_size,
                              hipStream_t stream) {
    const float* x   = (const float*)d_in[0];
    const int*   ei  = (const int*)d_in[1];   // [2,E]: src then dst
    const int*   bat = (const int*)d_in[2];
    const float* W1  = (const float*)d_in[4];
    const float* b1  = (const float*)d_in[5];
    const float* W2  = (const float*)d_in[6];
    const float* b2  = (const float*)d_in[7];
    const float* Wf  = (const float*)d_in[8];
    const float* bf  = (const float*)d_in[9];
    float* out = (float*)d_out;

    const int N = in_sizes[0];        // Fin = 1
    const int E = in_sizes[1] / 2;
    const int G = out_size / 16;

    const int* src = ei;
    const int* dst = ei + E;

    // workspace layout. zd overlays packed (dead after k_bucket_csr).
    char* w = (char*)d_ws;
    int*   bucketTot    = (int*)w;      w += NBUCK * 4;
    int*   bucketBase   = (int*)w;      w += (NBUCK + 1) * 4;
    int*   bucketCursor = (int*)w;      w += NBUCK * 4 + 256;  // pad
    int*   packed       = (int*)w;                 // [E] ints
    float* zd           = (float*)packed;          // [16N] overlay (16N*4 == E*4 here)
    w += (size_t)(E > 16 * N ? E : 16 * N) * 4;
    int*   csr      = (int*)w;          w += (size_t)E * 4;
    int*   cnt      = (int*)w;          w += (size_t)N * 4;
    int*   rowStart = (int*)w;          w += (size_t)N * 4;
    float* dinv     = (float*)w;        w += (size_t)N * 4;
    float* u        = (float*)w;        w += (size_t)N * 4;
    float* gsum     = (float*)w;        w += (size_t)16 * G * 4;
    float* cntf     = (float*)w;        w += (size_t)G * 4;
    float* M        = (float*)w;        w += 1024 * 4;
    float* bb       = (float*)w;

    const int chunk = cdiv(E, A2_BLOCKS);

    // CSR build: bucketed counting sort (atomics mostly in LDS)
    k_zero_i<<<1, NBUCK, 0, stream>>>(bucketTot, NBUCK);
    k_bhistA<<<256, 256, 0, stream>>>(dst, bucketTot, E);
    k_bscan<<<1, NBUCK, 0, stream>>>(bucketTot, bucketBase, bucketCursor);
    k_bscatter<<<A2_BLOCKS, 256, 0, stream>>>(src, dst, bucketCursor, packed, E, chunk);
    k_bucket_csr<<<cdiv(N, 256), 256, 0, stream>>>(bucketBase, packed, x,
                                                   cnt, rowStart, dinv, u, csr, N);

    // folded weights
    k_Mbb<<<1, 1024, 0, stream>>>(W2, Wf, b2, bf, M, bb);

    // layer-1 gather + transform -> zd (overlays packed, now dead)
    k_node<<<cdiv(N, TPB), TPB, 0, stream>>>(rowStart, cnt, csr, u, dinv, W1, b1, M, zd, N);

    // layer-2 gather + pool
    k_zero_f<<<cdiv(16 * G + G, TPB), TPB, 0, stream>>>(gsum, 16 * G + G);
    k_gather_pool<<<cdiv(N, 16), 256, 0, stream>>>(bat, rowStart, cnt, csr, zd, dinv, gsum, cntf, N);

    // finalize
    k_final<<<cdiv(G * 16, TPB), TPB, 0, stream>>>(gsum, cntf, bb, out, G);
}